// Round 6
// baseline (571.829 us; speedup 1.0000x reference)
//
#include <hip/hip_runtime.h>

typedef __attribute__((ext_vector_type(8))) _Float16 f16x8;
typedef __attribute__((ext_vector_type(4))) float f32x4;

#define S_LEN 2048
#define DMODEL 1024
#define NHEAD 16
#define HD 64
#define QKV_LD 3072
#define BTOT 4
#define LOG2E 1.4426950408889634f

#define GLL16(g, l)                                              \
  __builtin_amdgcn_global_load_lds(                              \
      (const __attribute__((address_space(1))) void*)(g),        \
      (__attribute__((address_space(3))) void*)(l), 16, 0, 0)

#define MFMA16(a, b, c) __builtin_amdgcn_mfma_f32_16x16x32_f16(a, b, c, 0, 0, 0)

// ---------------- fp32 -> fp16 elementwise convert ----------------
__global__ __launch_bounds__(256) void cvt_f32_f16_k(const float* __restrict__ in,
                                                     _Float16* __restrict__ out, int n) {
  int i = (blockIdx.x * 256 + threadIdx.x) * 4;
  int stride = gridDim.x * 256 * 4;
  for (; i < n; i += stride) {
    float4 v = *(const float4*)(in + i);
    _Float16 h[4];
    h[0] = (_Float16)v.x; h[1] = (_Float16)v.y; h[2] = (_Float16)v.z; h[3] = (_Float16)v.w;
    *(uint2*)(out + i) = *(const uint2*)h;
  }
}

// ---------------- fp32 [K][N] -> fp16 [N][K] transpose-convert ----------------
__global__ __launch_bounds__(256) void transpose_cvt_k(const float* __restrict__ W,
                                                       _Float16* __restrict__ Wt,
                                                       int K, int N) {
  __shared__ float t[32][33];
  int n0 = blockIdx.x * 32, k0 = blockIdx.y * 32;
  int tx = threadIdx.x, ty = threadIdx.y;  // (32,8)
#pragma unroll
  for (int i = 0; i < 32; i += 8)
    t[ty + i][tx] = W[(size_t)(k0 + ty + i) * N + n0 + tx];
  __syncthreads();
#pragma unroll
  for (int i = 0; i < 32; i += 8)
    Wt[(size_t)(n0 + ty + i) * K + k0 + tx] = (_Float16)t[tx][ty + i];
}

// ---------------- fp16 GEMM: C[M][N] = A[M][K] * Bt[N][K]^T + bias ----------------
// m97 structure + group-of-8 L2 supertile swizzle.
template <int OUT_F32>
__global__ __launch_bounds__(256) void gemm_bt_k(const _Float16* __restrict__ A,
                                                 const _Float16* __restrict__ Bt,
                                                 const float* __restrict__ bias,
                                                 void* __restrict__ C,
                                                 int M, int N, int K) {
  __shared__ _Float16 As[128 * 32];
  __shared__ _Float16 Bs[128 * 32];
  const int tid = threadIdx.x;
  const int wid = tid >> 6, lane = tid & 63;
  const int quad = lane >> 4, l16 = lane & 15;
  const int wr = wid >> 1, wc = wid & 1;

  const int lin = blockIdx.y * gridDim.x + blockIdx.x;
  const int width = 8 * gridDim.x;
  const int group = lin / width;
  const int pm = group * 8 + (lin % width) % 8;
  const int pn = (lin % width) / 8;
  const int tm = pm * 128, tn = pn * 128;

  const int sr = tid >> 2;
  const int scc = (tid & 3) * 8;
  const _Float16* Ag = A + (size_t)(tm + sr) * K + scc;
  const _Float16* Bg = Bt + (size_t)(tn + sr) * K + scc;
  _Float16* AsW = &As[wid * 512];
  _Float16* BsW = &Bs[wid * 512];

  f32x4 acc[4][4] = {};

  for (int k0 = 0; k0 < K; k0 += 32) {
    __syncthreads();
    GLL16(Ag + k0, AsW);
    GLL16(Ag + k0 + (size_t)64 * K, AsW + 2048);
    GLL16(Bg + k0, BsW);
    GLL16(Bg + k0 + (size_t)64 * K, BsW + 2048);
    __syncthreads();

    f16x8 af[4], bf[4];
#pragma unroll
    for (int mt = 0; mt < 4; mt++)
      af[mt] = *(const f16x8*)&As[(wr * 64 + mt * 16 + l16) * 32 + quad * 8];
#pragma unroll
    for (int nt = 0; nt < 4; nt++)
      bf[nt] = *(const f16x8*)&Bs[(wc * 64 + nt * 16 + l16) * 32 + quad * 8];
#pragma unroll
    for (int mt = 0; mt < 4; mt++)
#pragma unroll
      for (int nt = 0; nt < 4; nt++)
        acc[mt][nt] = MFMA16(af[mt], bf[nt], acc[mt][nt]);
  }

#pragma unroll
  for (int nt = 0; nt < 4; nt++) {
    int col = tn + wc * 64 + nt * 16 + l16;
    float bv = bias[col];
#pragma unroll
    for (int mt = 0; mt < 4; mt++) {
      int row = tm + wr * 64 + mt * 16 + quad * 4;
#pragma unroll
      for (int r = 0; r < 4; r++) {
        float v = acc[mt][nt][r] + bv;
        if (OUT_F32)
          ((float*)C)[(size_t)(row + r) * N + col] = v;
        else
          ((_Float16*)C)[(size_t)(row + r) * N + col] = (_Float16)v;
      }
    }
  }
}

// ---------------- fused causal flash attention ----------------
// Q-tile 128 (wave = 32 q), K-tile 64. S^T/O^T orientation. Q in registers.
// K fragments loaded DIRECTLY global->register (no K LDS: A-fragment is
// lane-contiguous 16B; K is L2-resident). V^T double-buffered in swizzled LDS
// (pair-pack staging). One barrier per K-tile. LDS ~35 KB -> 4 blocks/CU.
__global__ __launch_bounds__(256, 4) void attn_k(const _Float16* __restrict__ qkv,
                                                 _Float16* __restrict__ out) {
  __shared__ _Float16 VTs[2][4096];  // [d 64][k 64], chunk-swizzled, 16 KB
  __shared__ _Float16 Ps[4][2304];   // per-wave 32x72 P^T / epilogue, 18 KB

  const int tid = threadIdx.x, wid = tid >> 6, lane = tid & 63;
  const int quad = lane >> 4, l16 = lane & 15;
  const int qi = gridDim.x - 1 - blockIdx.x;  // longest-first for causal balance
  const int qt = qi * 128;
  const int bh = blockIdx.y, b = bh >> 4, h = bh & 15;
  const _Float16* base = qkv + (size_t)b * S_LEN * QKV_LD + h * HD;

  // ---- Q fragments in registers (B-operand layout), pre-scaled ----
  f16x8 bq[2][2];  // [nt][ks]
  {
    const _Float16 qs = (_Float16)(0.125f * LOG2E);
#pragma unroll
    for (int nt = 0; nt < 2; nt++)
#pragma unroll
      for (int ks = 0; ks < 2; ks++) {
        union { uint4 u; f16x8 h; } v;
        v.u = *(const uint4*)(base + (size_t)(qt + wid * 32 + nt * 16 + l16) * QKV_LD +
                              ks * 32 + quad * 8);
        bq[nt][ks] = v.h * qs;
      }
  }

  // K per-lane base: fragment (mt,ks) of tile k0 at Kl + (k0+mt*16)*LD + ks*32
  const _Float16* Kl = base + DMODEL + (size_t)l16 * QKV_LD + quad * 8;
  // V staging (pair-pack register transpose): rows 2kp,2kp+1, cols dbase..+7
  const int kp = tid & 31, dbase = (tid >> 5) * 8;
  const _Float16* Vg = base + 2 * DMODEL + (size_t)(2 * kp) * QKV_LD + dbase;

  auto stage_V = [&](int bufi, uint4 v0, uint4 v1) {
    union { uint4 u; _Float16 h[8]; } a, c;
    a.u = v0; c.u = v1;
    uint* VT32 = (uint*)VTs[bufi];
#pragma unroll
    for (int i = 0; i < 8; i++) {
      int d = dbase + i;
      union { _Float16 h[2]; uint u; } w;
      w.h[0] = a.h[i]; w.h[1] = c.h[i];
      VT32[d * 32 + (((kp >> 2) ^ (d & 7)) << 2) + (kp & 3)] = w.u;
    }
  };

  float m_i[2] = {-1e30f, -1e30f}, l_i[2] = {0.f, 0.f};
  f32x4 o[4][2] = {};  // O^T: rows d=md*16+quad*4+r, cols q=nt*16+l16

  const int qmin_w = qt + wid * 32;
  const int qmax_w = qmin_w + 31;
  const int nj = qt / 64 + 2;

  // ---- prologue: stage V tile 0 ----
  stage_V(0, *(const uint4*)(Vg), *(const uint4*)(Vg + QKV_LD));
  __syncthreads();

  for (int j = 0; j < nj; j++) {
    const int cur = j & 1, nxt = cur ^ 1;
    const int k0g = j * 64;
    const bool pf = (j + 1 < nj);
    uint4 pv0, pv1;
    if (pf) {
      const int kn = k0g + 64;
      pv0 = *(const uint4*)(Vg + (size_t)kn * QKV_LD);
      pv1 = *(const uint4*)(Vg + (size_t)(kn + 1) * QKV_LD);
    }

    if (k0g <= qmax_w) {
      // ---- K fragments: direct global->register (L2-resident) ----
      f16x8 ak[4][2];
#pragma unroll
      for (int mt = 0; mt < 4; mt++)
#pragma unroll
        for (int ks = 0; ks < 2; ks++)
          ak[mt][ks] = *(const f16x8*)(Kl + (size_t)(k0g + mt * 16) * QKV_LD + ks * 32);

      // ---- scores: S^T[64k][32q] ----
      f32x4 sc[4][2] = {};
#pragma unroll
      for (int ks = 0; ks < 2; ks++)
#pragma unroll
        for (int mt = 0; mt < 4; mt++) {
          sc[mt][0] = MFMA16(ak[mt][ks], bq[0][ks], sc[mt][0]);
          sc[mt][1] = MFMA16(ak[mt][ks], bq[1][ks], sc[mt][1]);
        }

      const bool need_mask = (k0g + 63 > qmin_w);
      float alpha[2];
#pragma unroll
      for (int nt = 0; nt < 2; nt++) {
        const int qg = qmin_w + nt * 16 + l16;
        float s[16];
#pragma unroll
        for (int mt = 0; mt < 4; mt++)
#pragma unroll
          for (int r = 0; r < 4; r++) {
            float v = sc[mt][nt][r];
            if (need_mask) {
              int kg = k0g + mt * 16 + quad * 4 + r;
              v = (kg <= qg) ? v : -3.0e38f;
            }
            s[mt * 4 + r] = v;
          }
        float mx = s[0];
#pragma unroll
        for (int i = 1; i < 16; i++) mx = fmaxf(mx, s[i]);
        mx = fmaxf(mx, __shfl_xor(mx, 16, 64));
        mx = fmaxf(mx, __shfl_xor(mx, 32, 64));
        float mnew = fmaxf(m_i[nt], mx);
        alpha[nt] = __builtin_amdgcn_exp2f(m_i[nt] - mnew);
        m_i[nt] = mnew;
        float rs = 0.f;
        _Float16 ph[16];
#pragma unroll
        for (int i = 0; i < 16; i++) {
          float p = __builtin_amdgcn_exp2f(s[i] - mnew);
          rs += p;
          ph[i] = (_Float16)p;
        }
        rs += __shfl_xor(rs, 16, 64);
        rs += __shfl_xor(rs, 32, 64);
        l_i[nt] = l_i[nt] * alpha[nt] + rs;
        // P^T quad-transpose via per-wave LDS (no barrier: DS wave-ordered)
#pragma unroll
        for (int mt = 0; mt < 4; mt++)
          *(uint2*)&Ps[wid][(nt * 16 + l16) * 72 + mt * 16 + quad * 4] = *(uint2*)&ph[mt * 4];
      }
#pragma unroll
      for (int md = 0; md < 4; md++) {
        o[md][0] *= alpha[0];
        o[md][1] *= alpha[1];
      }
      // ---- PV: O^T += V^T · P^T (swizzled VTs reads) ----
#pragma unroll
      for (int ks = 0; ks < 2; ks++) {
        f16x8 bp0 = *(const f16x8*)&Ps[wid][l16 * 72 + ks * 32 + quad * 8];
        f16x8 bp1 = *(const f16x8*)&Ps[wid][(16 + l16) * 72 + ks * 32 + quad * 8];
#pragma unroll
        for (int md = 0; md < 4; md++) {
          f16x8 av = *(const f16x8*)&VTs[cur][(md * 16 + l16) * 64 +
                                              (((ks * 4 + quad) ^ (l16 & 7)) << 3)];
          o[md][0] = MFMA16(av, bp0, o[md][0]);
          o[md][1] = MFMA16(av, bp1, o[md][1]);
        }
      }
    }

    if (pf) stage_V(nxt, pv0, pv1);
    __syncthreads();  // V(j+1) visible to all; V(j) reads done before its overwrite
  }

  // epilogue: normalize, transpose O^T->O via per-wave LDS, coalesced store
#pragma unroll
  for (int nt = 0; nt < 2; nt++) {
    float inv = 1.0f / l_i[nt];
#pragma unroll
    for (int md = 0; md < 4; md++) {
      _Float16 hh[4];
#pragma unroll
      for (int r = 0; r < 4; r++) hh[r] = (_Float16)(o[md][nt][r] * inv);
      *(uint2*)&Ps[wid][(nt * 16 + l16) * 72 + md * 16 + quad * 4] = *(uint2*)hh;
    }
  }
  {
    int r = lane >> 1, ch = (lane & 1) * 32;
    const int qg = qt + wid * 32 + r;
    _Float16* orow = out + (size_t)(b * S_LEN + qg) * DMODEL + h * HD + ch;
#pragma unroll
    for (int i = 0; i < 4; i++)
      *(uint4*)(orow + i * 8) = *(const uint4*)&Ps[wid][r * 72 + ch + i * 8];
  }
}

// ---------------- launcher ----------------
extern "C" void kernel_launch(void* const* d_in, const int* in_sizes, int n_in,
                              void* d_out, int out_size, void* d_ws, size_t ws_size,
                              hipStream_t stream) {
  const float* x = (const float*)d_in[0];
  const float* w_attn = (const float*)d_in[1];
  const float* b_attn = (const float*)d_in[2];
  const float* w_proj = (const float*)d_in[3];
  const float* b_proj = (const float*)d_in[4];
  float* outp = (float*)d_out;

  char* ws = (char*)d_ws;
  _Float16* x16 = (_Float16*)ws;                         // 16,777,216 B
  _Float16* wTa = (_Float16*)(ws + 16777216);            //  6,291,456 B
  _Float16* wTp = (_Float16*)(ws + 16777216 + 6291456);  //  2,097,152 B
  _Float16* qkv = (_Float16*)(ws + 25165824);            // 50,331,648 B
  _Float16* abuf = (_Float16*)(ws + 75497472);           // 16,777,216 B

  const int nx = BTOT * S_LEN * DMODEL;

  cvt_f32_f16_k<<<8192, 256, 0, stream>>>(x, x16, nx);
  transpose_cvt_k<<<dim3(QKV_LD / 32, DMODEL / 32), dim3(32, 8), 0, stream>>>(
      w_attn, wTa, DMODEL, QKV_LD);
  transpose_cvt_k<<<dim3(DMODEL / 32, DMODEL / 32), dim3(32, 8), 0, stream>>>(
      w_proj, wTp, DMODEL, DMODEL);

  gemm_bt_k<0><<<dim3(QKV_LD / 128, BTOT * S_LEN / 128), 256, 0, stream>>>(
      x16, wTa, b_attn, qkv, BTOT * S_LEN, QKV_LD, DMODEL);

  attn_k<<<dim3(S_LEN / 128, BTOT * NHEAD), 256, 0, stream>>>(qkv, abuf);

  gemm_bt_k<1><<<dim3(DMODEL / 128, BTOT * S_LEN / 128), 256, 0, stream>>>(
      abuf, wTp, b_proj, outp, BTOT * S_LEN, DMODEL, DMODEL);
}

// Round 7
// 366.990 us; speedup vs baseline: 1.5582x; 1.5582x over previous
//
#include <hip/hip_runtime.h>

typedef __attribute__((ext_vector_type(8))) _Float16 f16x8;
typedef __attribute__((ext_vector_type(4))) float f32x4;

#define S_LEN 2048
#define DMODEL 1024
#define NHEAD 16
#define HD 64
#define QKV_LD 3072
#define BTOT 4
#define LOG2E 1.4426950408889634f

#define GLL16(g, l)                                              \
  __builtin_amdgcn_global_load_lds(                              \
      (const __attribute__((address_space(1))) void*)(g),        \
      (__attribute__((address_space(3))) void*)(l), 16, 0, 0)

#define MFMA16(a, b, c) __builtin_amdgcn_mfma_f32_16x16x32_f16(a, b, c, 0, 0, 0)

// ---------------- fp32 -> fp16 elementwise convert ----------------
__global__ __launch_bounds__(256) void cvt_f32_f16_k(const float* __restrict__ in,
                                                     _Float16* __restrict__ out, int n) {
  int i = (blockIdx.x * 256 + threadIdx.x) * 4;
  int stride = gridDim.x * 256 * 4;
  for (; i < n; i += stride) {
    float4 v = *(const float4*)(in + i);
    _Float16 h[4];
    h[0] = (_Float16)v.x; h[1] = (_Float16)v.y; h[2] = (_Float16)v.z; h[3] = (_Float16)v.w;
    *(uint2*)(out + i) = *(const uint2*)h;
  }
}

// ---------------- fp32 [K][N] -> fp16 [N][K] transpose-convert ----------------
__global__ __launch_bounds__(256) void transpose_cvt_k(const float* __restrict__ W,
                                                       _Float16* __restrict__ Wt,
                                                       int K, int N) {
  __shared__ float t[32][33];
  int n0 = blockIdx.x * 32, k0 = blockIdx.y * 32;
  int tx = threadIdx.x, ty = threadIdx.y;  // (32,8)
#pragma unroll
  for (int i = 0; i < 32; i += 8)
    t[ty + i][tx] = W[(size_t)(k0 + ty + i) * N + n0 + tx];
  __syncthreads();
#pragma unroll
  for (int i = 0; i < 32; i += 8)
    Wt[(size_t)(n0 + ty + i) * K + k0 + tx] = (_Float16)t[tx][ty + i];
}

// ---------------- fp16 GEMM: C[M][N] = A[M][K] * Bt[N][K]^T + bias ----------------
// BK=64, swizzled LDS (conflict-free b128 reads) staged via source-column-XOR
// global_load_lds. 32 MFMAs per barrier-pair. L2 supertile swizzle.
template <int OUT_F32>
__global__ __launch_bounds__(256) void gemm_bt_k(const _Float16* __restrict__ A,
                                                 const _Float16* __restrict__ Bt,
                                                 const float* __restrict__ bias,
                                                 void* __restrict__ C,
                                                 int M, int N, int K) {
  __shared__ _Float16 As[128 * 64];  // 16 KB, chunk-swizzled
  __shared__ _Float16 Bs[128 * 64];  // 16 KB, chunk-swizzled
  const int tid = threadIdx.x;
  const int wid = tid >> 6, lane = tid & 63;
  const int quad = lane >> 4, l16 = lane & 15;
  const int wr = wid >> 1, wc = wid & 1;

  const int lin = blockIdx.y * gridDim.x + blockIdx.x;
  const int width = 8 * gridDim.x;
  const int group = lin / width;
  const int pm = group * 8 + (lin % width) % 8;
  const int pn = (lin % width) / 8;
  const int tm = pm * 128, tn = pn * 128;

  // staging: row tid>>3 (+32/pass), source col XORed so wave-linear LDS dest
  // lands the swizzle: phys chunk (tid&7) holds logical chunk (tid&7)^(row&7)
  const int row0 = tid >> 3;
  const int xc = 8 * ((tid & 7) ^ (row0 & 7));
  const _Float16* Ag = A + (size_t)(tm + row0) * K + xc;
  const _Float16* Bg = Bt + (size_t)(tn + row0) * K + xc;
  _Float16* AsW = &As[wid * 512];
  _Float16* BsW = &Bs[wid * 512];

  f32x4 acc[4][4] = {};

  for (int k0 = 0; k0 < K; k0 += 64) {
    __syncthreads();
#pragma unroll
    for (int p = 0; p < 4; p++) {
      GLL16(Ag + k0 + (size_t)(32 * p) * K, AsW + 2048 * p);
      GLL16(Bg + k0 + (size_t)(32 * p) * K, BsW + 2048 * p);
    }
    __syncthreads();

#pragma unroll
    for (int ks = 0; ks < 2; ks++) {
      f16x8 af[4], bf[4];
#pragma unroll
      for (int mt = 0; mt < 4; mt++)
        af[mt] = *(const f16x8*)&As[(wr * 64 + mt * 16 + l16) * 64 +
                                    (((ks * 4 + quad) ^ (l16 & 7)) << 3)];
#pragma unroll
      for (int nt = 0; nt < 4; nt++)
        bf[nt] = *(const f16x8*)&Bs[(wc * 64 + nt * 16 + l16) * 64 +
                                    (((ks * 4 + quad) ^ (l16 & 7)) << 3)];
#pragma unroll
      for (int mt = 0; mt < 4; mt++)
#pragma unroll
        for (int nt = 0; nt < 4; nt++)
          acc[mt][nt] = MFMA16(af[mt], bf[nt], acc[mt][nt]);
    }
  }

#pragma unroll
  for (int nt = 0; nt < 4; nt++) {
    int col = tn + wc * 64 + nt * 16 + l16;
    float bv = bias[col];
#pragma unroll
    for (int mt = 0; mt < 4; mt++) {
      int row = tm + wr * 64 + mt * 16 + quad * 4;
#pragma unroll
      for (int r = 0; r < 4; r++) {
        float v = acc[mt][nt][r] + bv;
        if (OUT_F32)
          ((float*)C)[(size_t)(row + r) * N + col] = v;
        else
          ((_Float16*)C)[(size_t)(row + r) * N + col] = (_Float16)v;
      }
    }
  }
}

// ---------------- fused causal flash attention ----------------
// R3 structure (proven 159us): Q-tile 128, K-tile 64, S^T/O^T orientation,
// Q in registers, double-buffered GLL K + pair-pack V^T, one barrier/iter.
// R7: + XOR chunk-swizzle on Ks (via source-col XOR) and VTs (proven in R5).
__global__ __launch_bounds__(256, 3) void attn_k(const _Float16* __restrict__ qkv,
                                                 _Float16* __restrict__ out) {
  __shared__ _Float16 Ks[2][4096];   // 2 x 8 KB  [k 64][d 64], chunk-swizzled
  __shared__ _Float16 VTs[2][4096];  // 2 x 8 KB  [d 64][k 64], chunk-swizzled
  __shared__ _Float16 Ps[4][2304];   // 18 KB per-wave 32x72 P^T / epilogue

  const int tid = threadIdx.x, wid = tid >> 6, lane = tid & 63;
  const int quad = lane >> 4, l16 = lane & 15;
  const int qi = gridDim.x - 1 - blockIdx.x;  // longest-first for causal balance
  const int qt = qi * 128;
  const int bh = blockIdx.y, b = bh >> 4, h = bh & 15;
  const _Float16* base = qkv + (size_t)b * S_LEN * QKV_LD + h * HD;

  // ---- Q fragments in registers (B-operand layout), pre-scaled ----
  f16x8 bq[2][2];  // [nt][ks]
  {
    const _Float16 qs = (_Float16)(0.125f * LOG2E);
#pragma unroll
    for (int nt = 0; nt < 2; nt++)
#pragma unroll
      for (int ks = 0; ks < 2; ks++) {
        union { uint4 u; f16x8 h; } v;
        v.u = *(const uint4*)(base + (size_t)(qt + wid * 32 + nt * 16 + l16) * QKV_LD +
                              ks * 32 + quad * 8);
        bq[nt][ks] = v.h * qs;
      }
  }

  // K staging via GLL, source-col XOR -> swizzled LDS layout
  const int krow = tid >> 3;
  const _Float16* Kg = base + DMODEL + (size_t)krow * QKV_LD +
                       8 * ((tid & 7) ^ (krow & 7));
  // V staging (pair-pack register transpose, swizzled): rows 2kp,2kp+1
  const int kp = tid & 31, dbase = (tid >> 5) * 8;
  const _Float16* Vg = base + 2 * DMODEL + (size_t)(2 * kp) * QKV_LD + dbase;

  auto stage_V = [&](int bufi, uint4 v0, uint4 v1) {
    union { uint4 u; _Float16 h[8]; } a, c;
    a.u = v0; c.u = v1;
    uint* VT32 = (uint*)VTs[bufi];
#pragma unroll
    for (int i = 0; i < 8; i++) {
      int d = dbase + i;
      union { _Float16 h[2]; uint u; } w;
      w.h[0] = a.h[i]; w.h[1] = c.h[i];
      VT32[d * 32 + (((kp >> 2) ^ (d & 7)) << 2) + (kp & 3)] = w.u;
    }
  };

  float m_i[2] = {-1e30f, -1e30f}, l_i[2] = {0.f, 0.f};
  f32x4 o[4][2] = {};  // O^T: rows d=md*16+quad*4+r, cols q=nt*16+l16

  const int qmin_w = qt + wid * 32;
  const int qmax_w = qmin_w + 31;
  const int nj = qt / 64 + 2;

  // ---- prologue: stage tile 0 ----
  GLL16(Kg, &Ks[0][wid * 512]);
  GLL16(Kg + (size_t)32 * QKV_LD, &Ks[0][2048 + wid * 512]);
  stage_V(0, *(const uint4*)(Vg), *(const uint4*)(Vg + QKV_LD));
  __syncthreads();

  for (int j = 0; j < nj; j++) {
    const int cur = j & 1, nxt = cur ^ 1;
    const int k0g = j * 64;
    const bool pf = (j + 1 < nj);
    uint4 pv0, pv1;
    if (pf) {
      const int kn = k0g + 64;
      GLL16(Kg + (size_t)kn * QKV_LD, &Ks[nxt][wid * 512]);
      GLL16(Kg + (size_t)(kn + 32) * QKV_LD, &Ks[nxt][2048 + wid * 512]);
      pv0 = *(const uint4*)(Vg + (size_t)kn * QKV_LD);
      pv1 = *(const uint4*)(Vg + (size_t)(kn + 1) * QKV_LD);
    }

    if (k0g <= qmax_w) {
      // ---- scores: S^T[64k][32q] ----
      f32x4 sc[4][2] = {};
#pragma unroll
      for (int ks = 0; ks < 2; ks++) {
#pragma unroll
        for (int mt = 0; mt < 4; mt++) {
          f16x8 ak = *(const f16x8*)&Ks[cur][(mt * 16 + l16) * 64 +
                                             (((ks * 4 + quad) ^ (l16 & 7)) << 3)];
          sc[mt][0] = MFMA16(ak, bq[0][ks], sc[mt][0]);
          sc[mt][1] = MFMA16(ak, bq[1][ks], sc[mt][1]);
        }
      }

      const bool need_mask = (k0g + 63 > qmin_w);
      float alpha[2];
#pragma unroll
      for (int nt = 0; nt < 2; nt++) {
        const int qg = qmin_w + nt * 16 + l16;
        float s[16];
#pragma unroll
        for (int mt = 0; mt < 4; mt++)
#pragma unroll
          for (int r = 0; r < 4; r++) {
            float v = sc[mt][nt][r];
            if (need_mask) {
              int kg = k0g + mt * 16 + quad * 4 + r;
              v = (kg <= qg) ? v : -3.0e38f;
            }
            s[mt * 4 + r] = v;
          }
        float mx = s[0];
#pragma unroll
        for (int i = 1; i < 16; i++) mx = fmaxf(mx, s[i]);
        mx = fmaxf(mx, __shfl_xor(mx, 16, 64));
        mx = fmaxf(mx, __shfl_xor(mx, 32, 64));
        float mnew = fmaxf(m_i[nt], mx);
        alpha[nt] = __builtin_amdgcn_exp2f(m_i[nt] - mnew);
        m_i[nt] = mnew;
        float rs = 0.f;
        _Float16 ph[16];
#pragma unroll
        for (int i = 0; i < 16; i++) {
          float p = __builtin_amdgcn_exp2f(s[i] - mnew);
          rs += p;
          ph[i] = (_Float16)p;
        }
        rs += __shfl_xor(rs, 16, 64);
        rs += __shfl_xor(rs, 32, 64);
        l_i[nt] = l_i[nt] * alpha[nt] + rs;
        // P^T quad-transpose via per-wave LDS (no barrier: DS wave-ordered)
#pragma unroll
        for (int mt = 0; mt < 4; mt++)
          *(uint2*)&Ps[wid][(nt * 16 + l16) * 72 + mt * 16 + quad * 4] = *(uint2*)&ph[mt * 4];
      }
#pragma unroll
      for (int md = 0; md < 4; md++) {
        o[md][0] *= alpha[0];
        o[md][1] *= alpha[1];
      }
      // ---- PV: O^T += V^T · P^T (swizzled VTs reads) ----
#pragma unroll
      for (int ks = 0; ks < 2; ks++) {
        f16x8 bp0 = *(const f16x8*)&Ps[wid][l16 * 72 + ks * 32 + quad * 8];
        f16x8 bp1 = *(const f16x8*)&Ps[wid][(16 + l16) * 72 + ks * 32 + quad * 8];
#pragma unroll
        for (int md = 0; md < 4; md++) {
          f16x8 av = *(const f16x8*)&VTs[cur][(md * 16 + l16) * 64 +
                                              (((ks * 4 + quad) ^ (l16 & 7)) << 3)];
          o[md][0] = MFMA16(av, bp0, o[md][0]);
          o[md][1] = MFMA16(av, bp1, o[md][1]);
        }
      }
    }

    if (pf) stage_V(nxt, pv0, pv1);
    __syncthreads();  // drains GLL K(j+1) + V writes; frees cur for next prefetch
  }

  // epilogue: normalize, transpose O^T->O via per-wave LDS, coalesced store
#pragma unroll
  for (int nt = 0; nt < 2; nt++) {
    float inv = 1.0f / l_i[nt];
#pragma unroll
    for (int md = 0; md < 4; md++) {
      _Float16 hh[4];
#pragma unroll
      for (int r = 0; r < 4; r++) hh[r] = (_Float16)(o[md][nt][r] * inv);
      *(uint2*)&Ps[wid][(nt * 16 + l16) * 72 + md * 16 + quad * 4] = *(uint2*)hh;
    }
  }
  {
    int r = lane >> 1, ch = (lane & 1) * 32;
    const int qg = qt + wid * 32 + r;
    _Float16* orow = out + (size_t)(b * S_LEN + qg) * DMODEL + h * HD + ch;
#pragma unroll
    for (int i = 0; i < 4; i++)
      *(uint4*)(orow + i * 8) = *(const uint4*)&Ps[wid][r * 72 + ch + i * 8];
  }
}

// ---------------- launcher ----------------
extern "C" void kernel_launch(void* const* d_in, const int* in_sizes, int n_in,
                              void* d_out, int out_size, void* d_ws, size_t ws_size,
                              hipStream_t stream) {
  const float* x = (const float*)d_in[0];
  const float* w_attn = (const float*)d_in[1];
  const float* b_attn = (const float*)d_in[2];
  const float* w_proj = (const float*)d_in[3];
  const float* b_proj = (const float*)d_in[4];
  float* outp = (float*)d_out;

  char* ws = (char*)d_ws;
  _Float16* x16 = (_Float16*)ws;                         // 16,777,216 B
  _Float16* wTa = (_Float16*)(ws + 16777216);            //  6,291,456 B
  _Float16* wTp = (_Float16*)(ws + 16777216 + 6291456);  //  2,097,152 B
  _Float16* qkv = (_Float16*)(ws + 25165824);            // 50,331,648 B
  _Float16* abuf = (_Float16*)(ws + 75497472);           // 16,777,216 B

  const int nx = BTOT * S_LEN * DMODEL;

  cvt_f32_f16_k<<<8192, 256, 0, stream>>>(x, x16, nx);
  transpose_cvt_k<<<dim3(QKV_LD / 32, DMODEL / 32), dim3(32, 8), 0, stream>>>(
      w_attn, wTa, DMODEL, QKV_LD);
  transpose_cvt_k<<<dim3(DMODEL / 32, DMODEL / 32), dim3(32, 8), 0, stream>>>(
      w_proj, wTp, DMODEL, DMODEL);

  gemm_bt_k<0><<<dim3(QKV_LD / 128, BTOT * S_LEN / 128), 256, 0, stream>>>(
      x16, wTa, b_attn, qkv, BTOT * S_LEN, QKV_LD, DMODEL);

  attn_k<<<dim3(S_LEN / 128, BTOT * NHEAD), 256, 0, stream>>>(qkv, abuf);

  gemm_bt_k<1><<<dim3(DMODEL / 128, BTOT * S_LEN / 128), 256, 0, stream>>>(
      abuf, wTp, b_proj, outp, BTOT * S_LEN, DMODEL, DMODEL);
}

// Round 8
// 271.287 us; speedup vs baseline: 2.1078x; 1.3528x over previous
//
#include <hip/hip_runtime.h>

typedef __attribute__((ext_vector_type(8))) _Float16 f16x8;
typedef __attribute__((ext_vector_type(4))) float f32x4;

#define S_LEN 2048
#define DMODEL 1024
#define NHEAD 16
#define HD 64
#define QKV_LD 3072
#define BTOT 4
#define LOG2E 1.4426950408889634f

#define GLL16(g, l)                                              \
  __builtin_amdgcn_global_load_lds(                              \
      (const __attribute__((address_space(1))) void*)(g),        \
      (__attribute__((address_space(3))) void*)(l), 16, 0, 0)

#define MFMA16(a, b, c) __builtin_amdgcn_mfma_f32_16x16x32_f16(a, b, c, 0, 0, 0)

// ---------------- fp32 -> fp16 elementwise convert ----------------
__global__ __launch_bounds__(256) void cvt_f32_f16_k(const float* __restrict__ in,
                                                     _Float16* __restrict__ out, int n) {
  int i = (blockIdx.x * 256 + threadIdx.x) * 4;
  int stride = gridDim.x * 256 * 4;
  for (; i < n; i += stride) {
    float4 v = *(const float4*)(in + i);
    _Float16 h[4];
    h[0] = (_Float16)v.x; h[1] = (_Float16)v.y; h[2] = (_Float16)v.z; h[3] = (_Float16)v.w;
    *(uint2*)(out + i) = *(const uint2*)h;
  }
}

// ---------------- fp32 [K][N] -> fp16 [N][K] transpose-convert ----------------
__global__ __launch_bounds__(256) void transpose_cvt_k(const float* __restrict__ W,
                                                       _Float16* __restrict__ Wt,
                                                       int K, int N) {
  __shared__ float t[32][33];
  int n0 = blockIdx.x * 32, k0 = blockIdx.y * 32;
  int tx = threadIdx.x, ty = threadIdx.y;  // (32,8)
#pragma unroll
  for (int i = 0; i < 32; i += 8)
    t[ty + i][tx] = W[(size_t)(k0 + ty + i) * N + n0 + tx];
  __syncthreads();
#pragma unroll
  for (int i = 0; i < 32; i += 8)
    Wt[(size_t)(n0 + ty + i) * K + k0 + tx] = (_Float16)t[tx][ty + i];
}

// ---------------- fp16 GEMM: C[M][N] = A[M][K] * Bt[N][K]^T + bias ----------------
// BK=64, swizzled LDS (conflict-free b128 reads) staged via source-column-XOR
// global_load_lds. 32 MFMAs per barrier-pair. L2 supertile swizzle.
template <int OUT_F32>
__global__ __launch_bounds__(256) void gemm_bt_k(const _Float16* __restrict__ A,
                                                 const _Float16* __restrict__ Bt,
                                                 const float* __restrict__ bias,
                                                 void* __restrict__ C,
                                                 int M, int N, int K) {
  __shared__ _Float16 As[128 * 64];  // 16 KB, chunk-swizzled
  __shared__ _Float16 Bs[128 * 64];  // 16 KB, chunk-swizzled
  const int tid = threadIdx.x;
  const int wid = tid >> 6, lane = tid & 63;
  const int quad = lane >> 4, l16 = lane & 15;
  const int wr = wid >> 1, wc = wid & 1;

  const int lin = blockIdx.y * gridDim.x + blockIdx.x;
  const int width = 8 * gridDim.x;
  const int group = lin / width;
  const int pm = group * 8 + (lin % width) % 8;
  const int pn = (lin % width) / 8;
  const int tm = pm * 128, tn = pn * 128;

  const int row0 = tid >> 3;
  const int xc = 8 * ((tid & 7) ^ (row0 & 7));
  const _Float16* Ag = A + (size_t)(tm + row0) * K + xc;
  const _Float16* Bg = Bt + (size_t)(tn + row0) * K + xc;
  _Float16* AsW = &As[wid * 512];
  _Float16* BsW = &Bs[wid * 512];

  f32x4 acc[4][4] = {};

  for (int k0 = 0; k0 < K; k0 += 64) {
    __syncthreads();
#pragma unroll
    for (int p = 0; p < 4; p++) {
      GLL16(Ag + k0 + (size_t)(32 * p) * K, AsW + 2048 * p);
      GLL16(Bg + k0 + (size_t)(32 * p) * K, BsW + 2048 * p);
    }
    __syncthreads();

#pragma unroll
    for (int ks = 0; ks < 2; ks++) {
      f16x8 af[4], bf[4];
#pragma unroll
      for (int mt = 0; mt < 4; mt++)
        af[mt] = *(const f16x8*)&As[(wr * 64 + mt * 16 + l16) * 64 +
                                    (((ks * 4 + quad) ^ (l16 & 7)) << 3)];
#pragma unroll
      for (int nt = 0; nt < 4; nt++)
        bf[nt] = *(const f16x8*)&Bs[(wc * 64 + nt * 16 + l16) * 64 +
                                    (((ks * 4 + quad) ^ (l16 & 7)) << 3)];
#pragma unroll
      for (int mt = 0; mt < 4; mt++)
#pragma unroll
        for (int nt = 0; nt < 4; nt++)
          acc[mt][nt] = MFMA16(af[mt], bf[nt], acc[mt][nt]);
    }
  }

#pragma unroll
  for (int nt = 0; nt < 4; nt++) {
    int col = tn + wc * 64 + nt * 16 + l16;
    float bv = bias[col];
#pragma unroll
    for (int mt = 0; mt < 4; mt++) {
      int row = tm + wr * 64 + mt * 16 + quad * 4;
#pragma unroll
      for (int r = 0; r < 4; r++) {
        float v = acc[mt][nt][r] + bv;
        if (OUT_F32)
          ((float*)C)[(size_t)(row + r) * N + col] = v;
        else
          ((_Float16*)C)[(size_t)(row + r) * N + col] = (_Float16)v;
      }
    }
  }
}

// ---------------- fused causal flash attention ----------------
// R8: uniform paired blocks. Block (bh, p) processes q-tiles p then 15-p of the
// same head SEQUENTIALLY -> every block runs exactly 34 K-tile iterations (zero
// drain tail; this was the R7 bottleneck: occupancy 12.6% from skewed blocks).
// Per-pass structure = R3/R7: Q-tile 128, K-tile 64, S^T/O^T, Q in registers,
// double-buffered GLL K + pair-pack V^T (both XOR-chunk-swizzled), 1 barrier/iter.
// Grid (bh=64, p=8): a head's 8 blocks share linear%8 -> same XCD L2.
__global__ __launch_bounds__(256, 3) void attn_k(const _Float16* __restrict__ qkv,
                                                 _Float16* __restrict__ out) {
  __shared__ _Float16 Ks[2][4096];   // 2 x 8 KB  [k 64][d 64], chunk-swizzled
  __shared__ _Float16 VTs[2][4096];  // 2 x 8 KB  [d 64][k 64], chunk-swizzled
  __shared__ _Float16 Ps[4][2304];   // 18 KB per-wave 32x72 P^T / epilogue

  const int tid = threadIdx.x, wid = tid >> 6, lane = tid & 63;
  const int quad = lane >> 4, l16 = lane & 15;
  const int bh = blockIdx.x, b = bh >> 4, h = bh & 15;
  const int p = blockIdx.y;  // 0..7
  const _Float16* base = qkv + (size_t)b * S_LEN * QKV_LD + h * HD;

  // K staging via GLL, source-col XOR -> swizzled LDS layout
  const int krow = tid >> 3;
  const _Float16* Kg = base + DMODEL + (size_t)krow * QKV_LD +
                       8 * ((tid & 7) ^ (krow & 7));
  // V staging (pair-pack register transpose, swizzled): rows 2kp,2kp+1
  const int kp = tid & 31, dbase = (tid >> 5) * 8;
  const _Float16* Vg = base + 2 * DMODEL + (size_t)(2 * kp) * QKV_LD + dbase;

  auto stage_V = [&](int bufi, uint4 v0, uint4 v1) {
    union { uint4 u; _Float16 h[8]; } a, c;
    a.u = v0; c.u = v1;
    uint* VT32 = (uint*)VTs[bufi];
#pragma unroll
    for (int i = 0; i < 8; i++) {
      int d = dbase + i;
      union { _Float16 h[2]; uint u; } w;
      w.h[0] = a.h[i]; w.h[1] = c.h[i];
      VT32[d * 32 + (((kp >> 2) ^ (d & 7)) << 2) + (kp & 3)] = w.u;
    }
  };

  auto run_pass = [&](int qt) {
    // ---- Q fragments in registers (B-operand layout), pre-scaled ----
    f16x8 bq[2][2];  // [nt][ks]
    {
      const _Float16 qs = (_Float16)(0.125f * LOG2E);
#pragma unroll
      for (int nt = 0; nt < 2; nt++)
#pragma unroll
        for (int ks = 0; ks < 2; ks++) {
          union { uint4 u; f16x8 h; } v;
          v.u = *(const uint4*)(base + (size_t)(qt + wid * 32 + nt * 16 + l16) * QKV_LD +
                                ks * 32 + quad * 8);
          bq[nt][ks] = v.h * qs;
        }
    }

    float m_i[2] = {-1e30f, -1e30f}, l_i[2] = {0.f, 0.f};
    f32x4 o[4][2] = {};  // O^T: rows d=md*16+quad*4+r, cols q=nt*16+l16

    const int qmin_w = qt + wid * 32;
    const int qmax_w = qmin_w + 31;
    const int nj = qt / 64 + 2;

    // ---- prologue: stage tile 0 ----
    GLL16(Kg, &Ks[0][wid * 512]);
    GLL16(Kg + (size_t)32 * QKV_LD, &Ks[0][2048 + wid * 512]);
    stage_V(0, *(const uint4*)(Vg), *(const uint4*)(Vg + QKV_LD));
    __syncthreads();

    for (int j = 0; j < nj; j++) {
      const int cur = j & 1, nxt = cur ^ 1;
      const int k0g = j * 64;
      const bool pf = (j + 1 < nj);
      uint4 pv0, pv1;
      if (pf) {
        const int kn = k0g + 64;
        GLL16(Kg + (size_t)kn * QKV_LD, &Ks[nxt][wid * 512]);
        GLL16(Kg + (size_t)(kn + 32) * QKV_LD, &Ks[nxt][2048 + wid * 512]);
        pv0 = *(const uint4*)(Vg + (size_t)kn * QKV_LD);
        pv1 = *(const uint4*)(Vg + (size_t)(kn + 1) * QKV_LD);
      }

      if (k0g <= qmax_w) {
        // ---- scores: S^T[64k][32q] ----
        f32x4 sc[4][2] = {};
#pragma unroll
        for (int ks = 0; ks < 2; ks++) {
#pragma unroll
          for (int mt = 0; mt < 4; mt++) {
            f16x8 ak = *(const f16x8*)&Ks[cur][(mt * 16 + l16) * 64 +
                                               (((ks * 4 + quad) ^ (l16 & 7)) << 3)];
            sc[mt][0] = MFMA16(ak, bq[0][ks], sc[mt][0]);
            sc[mt][1] = MFMA16(ak, bq[1][ks], sc[mt][1]);
          }
        }

        const bool need_mask = (k0g + 63 > qmin_w);
        float alpha[2];
#pragma unroll
        for (int nt = 0; nt < 2; nt++) {
          const int qg = qmin_w + nt * 16 + l16;
          float s[16];
#pragma unroll
          for (int mt = 0; mt < 4; mt++)
#pragma unroll
            for (int r = 0; r < 4; r++) {
              float v = sc[mt][nt][r];
              if (need_mask) {
                int kg = k0g + mt * 16 + quad * 4 + r;
                v = (kg <= qg) ? v : -3.0e38f;
              }
              s[mt * 4 + r] = v;
            }
          float mx = s[0];
#pragma unroll
          for (int i = 1; i < 16; i++) mx = fmaxf(mx, s[i]);
          mx = fmaxf(mx, __shfl_xor(mx, 16, 64));
          mx = fmaxf(mx, __shfl_xor(mx, 32, 64));
          float mnew = fmaxf(m_i[nt], mx);
          alpha[nt] = __builtin_amdgcn_exp2f(m_i[nt] - mnew);
          m_i[nt] = mnew;
          float rs = 0.f;
          _Float16 ph[16];
#pragma unroll
          for (int i = 0; i < 16; i++) {
            float pv = __builtin_amdgcn_exp2f(s[i] - mnew);
            rs += pv;
            ph[i] = (_Float16)pv;
          }
          rs += __shfl_xor(rs, 16, 64);
          rs += __shfl_xor(rs, 32, 64);
          l_i[nt] = l_i[nt] * alpha[nt] + rs;
          // P^T quad-transpose via per-wave LDS (no barrier: DS wave-ordered)
#pragma unroll
          for (int mt = 0; mt < 4; mt++)
            *(uint2*)&Ps[wid][(nt * 16 + l16) * 72 + mt * 16 + quad * 4] =
                *(uint2*)&ph[mt * 4];
        }
#pragma unroll
        for (int md = 0; md < 4; md++) {
          o[md][0] *= alpha[0];
          o[md][1] *= alpha[1];
        }
        // ---- PV: O^T += V^T · P^T (swizzled VTs reads) ----
#pragma unroll
        for (int ks = 0; ks < 2; ks++) {
          f16x8 bp0 = *(const f16x8*)&Ps[wid][l16 * 72 + ks * 32 + quad * 8];
          f16x8 bp1 = *(const f16x8*)&Ps[wid][(16 + l16) * 72 + ks * 32 + quad * 8];
#pragma unroll
          for (int md = 0; md < 4; md++) {
            f16x8 av = *(const f16x8*)&VTs[cur][(md * 16 + l16) * 64 +
                                                (((ks * 4 + quad) ^ (l16 & 7)) << 3)];
            o[md][0] = MFMA16(av, bp0, o[md][0]);
            o[md][1] = MFMA16(av, bp1, o[md][1]);
          }
        }
      }

      if (pf) stage_V(nxt, pv0, pv1);
      __syncthreads();  // drains GLL K(j+1) + V writes; frees cur for next prefetch
    }

    // epilogue: normalize, transpose O^T->O via per-wave LDS, coalesced store
#pragma unroll
    for (int nt = 0; nt < 2; nt++) {
      float inv = 1.0f / l_i[nt];
#pragma unroll
      for (int md = 0; md < 4; md++) {
        _Float16 hh[4];
#pragma unroll
        for (int r = 0; r < 4; r++) hh[r] = (_Float16)(o[md][nt][r] * inv);
        *(uint2*)&Ps[wid][(nt * 16 + l16) * 72 + md * 16 + quad * 4] = *(uint2*)hh;
      }
    }
    {
      int r = lane >> 1, ch = (lane & 1) * 32;
      const int qg = qt + wid * 32 + r;
      _Float16* orow = out + (size_t)(b * S_LEN + qg) * DMODEL + h * HD + ch;
#pragma unroll
      for (int i = 0; i < 4; i++)
        *(uint4*)(orow + i * 8) = *(const uint4*)&Ps[wid][r * 72 + ch + i * 8];
    }
  };

  // short pass first, then long (long re-reads short's K/V tiles while L2-warm)
  run_pass(p * 128);
  run_pass((15 - p) * 128);
}

// ---------------- launcher ----------------
extern "C" void kernel_launch(void* const* d_in, const int* in_sizes, int n_in,
                              void* d_out, int out_size, void* d_ws, size_t ws_size,
                              hipStream_t stream) {
  const float* x = (const float*)d_in[0];
  const float* w_attn = (const float*)d_in[1];
  const float* b_attn = (const float*)d_in[2];
  const float* w_proj = (const float*)d_in[3];
  const float* b_proj = (const float*)d_in[4];
  float* outp = (float*)d_out;

  char* ws = (char*)d_ws;
  _Float16* x16 = (_Float16*)ws;                         // 16,777,216 B
  _Float16* wTa = (_Float16*)(ws + 16777216);            //  6,291,456 B
  _Float16* wTp = (_Float16*)(ws + 16777216 + 6291456);  //  2,097,152 B
  _Float16* qkv = (_Float16*)(ws + 25165824);            // 50,331,648 B
  _Float16* abuf = (_Float16*)(ws + 75497472);           // 16,777,216 B

  const int nx = BTOT * S_LEN * DMODEL;

  cvt_f32_f16_k<<<8192, 256, 0, stream>>>(x, x16, nx);
  transpose_cvt_k<<<dim3(QKV_LD / 32, DMODEL / 32), dim3(32, 8), 0, stream>>>(
      w_attn, wTa, DMODEL, QKV_LD);
  transpose_cvt_k<<<dim3(DMODEL / 32, DMODEL / 32), dim3(32, 8), 0, stream>>>(
      w_proj, wTp, DMODEL, DMODEL);

  gemm_bt_k<0><<<dim3(QKV_LD / 128, BTOT * S_LEN / 128), 256, 0, stream>>>(
      x16, wTa, b_attn, qkv, BTOT * S_LEN, QKV_LD, DMODEL);

  attn_k<<<dim3(BTOT * NHEAD, 8), 256, 0, stream>>>(qkv, abuf);

  gemm_bt_k<1><<<dim3(DMODEL / 128, BTOT * S_LEN / 128), 256, 0, stream>>>(
      abuf, wTp, b_proj, outp, BTOT * S_LEN, DMODEL, DMODEL);
}